// Round 19
// baseline (404.350 us; speedup 1.0000x reference)
//
#include <hip/hip_runtime.h>

// ForwardSim: B=32768, T=50 sequential steps of a 267->128->128->1 MLP.
// R1 1087 / R5 445 / R6 402 (producer-split packed h1) / R7 828 REGRESSION
//   (launch_bounds(,4) -> VGPR 64 -> W2 spill) / R8 387 (bounds(,2): 4-wave
//   blocks, 4 barrier domains/CU; rocprof 283us, VALU 52%, Mfma 30%).
// R9: 2 barriers/step (was 3). (a) Layer-2 computed TRANSPOSED:
//   MFMA(A=w2 frags, B=h1 frags) - same registers, same LDS reads, swapped
//   operands -> each lane's 16 acc values = 16 out-dims of ONE batch row
//   (col=lane=row). Layer-3 row-sum becomes 16 in-reg adds + shfl_xor(32)
//   + 4-float partial/wave: the whole s_p round-trip (16 wr + barrier +
//   16 rd) is gone. (b) Per-row state replicated in lanes l31=row; env
//   built in-register -> s_env + its barrier gone. b2/W3 per-reg constants
//   come from a 1KB LDS table (transient reads; keeps VGPR ~104, avoiding
//   R7's spill). LDS 36.3KB -> ~18.5KB. Same split/MFMA math; only the
//   final 128-term fp32 sum order changes (b2=0 in harness -> exact).
// (R9 resubmitted: five GPUAcquisitionTimeouts in a row — no bench signal.
//  Static audits r14-r16: transpose layout, split terms, hazards, shfl
//  width, writer uniqueness, VGPR/LDS budget all clean.)

using bf16x8 = __attribute__((ext_vector_type(8))) short;
using f32x16 = __attribute__((ext_vector_type(16))) float;
using u32x4  = __attribute__((ext_vector_type(4))) unsigned int;

constexpr int B_TOT   = 32768;
constexpr int T_STEPS = 50;
constexpr int FEATC   = 14;
constexpr int MDC     = 3;
constexpr float ALPHA_C = 0.3f;
constexpr float DT_C    = 0.1f;

constexpr int NB   = 32;     // batch rows per block
constexpr int NTHR = 256;    // 4 waves; wave nq owns out-dims nq*32..nq*32+31
constexpr int PS   = 132;    // s_h1p dword stride (b128-aligned, 4-way alias floor)

__device__ __forceinline__ float leaky(float x) { return fmaxf(x, ALPHA_C * x); }

// split fp32 into bf16 hi (truncate) + bf16 lo (truncated exact residual)
__device__ __forceinline__ short2 split1(float x) {
    unsigned u = __float_as_uint(x);
    short h = (short)(u >> 16);
    float r = x - __uint_as_float(u & 0xFFFF0000u);   // exact in fp32
    short l = (short)(__float_as_uint(r) >> 16);
    return make_short2(h, l);
}

// packed split: low16 = hi bf16, high16 = lo bf16
__device__ __forceinline__ unsigned packsplit(float x) {
    unsigned u = __float_as_uint(x);
    float r = x - __uint_as_float(u & 0xFFFF0000u);
    return (u >> 16) | (__float_as_uint(r) & 0xFFFF0000u);
}

#define MFMA(A, B, C) __builtin_amdgcn_mfma_f32_32x32x16_bf16(A, B, C, 0, 0, 0)

__launch_bounds__(NTHR, 2)
__global__ void fwd_sim(const float* __restrict__ proj,
                        const float* __restrict__ enc,
                        const float* __restrict__ idm,
                        const float* __restrict__ mc,
                        const float* __restrict__ env_mean,
                        const float* __restrict__ env_var,
                        const float* __restrict__ W1,
                        const float* __restrict__ b1,
                        const float* __restrict__ W2,
                        const float* __restrict__ b2,
                        const float* __restrict__ W3,
                        const float* __restrict__ b3,
                        float* __restrict__ out)
{
    __shared__ unsigned s_h1p[NB * PS];   // h1 packed (hi|lo<<16), P1 -> P3
    __shared__ float    s_part[NB * 4];   // layer-3 partial sums [row][wave]
    __shared__ float    s_bw[256];        // (b2[out], W3[out]) interleaved

    const int tid  = threadIdx.x;
    const int lane = tid & 63;
    const int nq   = tid >> 6;        // wave 0..3 = out-quarter
    const int l31  = lane & 31;       // batch row (and out-col-local)
    const int half = lane >> 5;       // k-half within fragment
    const int ncol = nq * 32 + l31;   // out-dim for weight frags
    const int b_base = blockIdx.x * NB;
    const long ACT_OFF = (long)B_TOT * 51;

    // stage (b2, W3) pairs; ordered before first P3 by barrier A of t=0
    for (int i = tid; i < 128; i += NTHR) {
        s_bw[2 * i]     = b2[i];
        s_bw[2 * i + 1] = W3[i];
    }

    // phase base pointers
    unsigned*       wp  = s_h1p + (4 * half) * PS + ncol;  // P1 packed write
    const unsigned* rp  = s_h1p + l31 * PS + half * 8;     // P3 fragment read
    const float*    bwp = s_bw + 2 * (nq * 32 + 4 * half); // epilogue consts

    // ---- W2 pre-split fragments (per-lane W2[k][ncol]) -- used as A (=W2^T) ----
    bf16x8 w2h[8], w2l[8];
    for (int kb = 0; kb < 8; ++kb) {
        #pragma unroll
        for (int j = 0; j < 8; ++j) {
            short2 s = split1(W2[(kb * 16 + half * 8 + j) * 128 + ncol]);
            w2h[kb][j] = s.x; w2l[kb][j] = s.y;
        }
    }
    // ---- W1 rows 256..266 (env+mc), K padded to 16 ----
    bf16x8 w1xh, w1xl;
    #pragma unroll
    for (int j = 0; j < 8; ++j) {
        int k = half * 8 + j;
        short2 s = split1(k < 11 ? W1[(256 + k) * 128 + ncol] : 0.f);
        w1xh[j] = s.x; w1xl[j] = s.y;
    }

    // ---- base1 = b1 + [proj|enc] @ W1[0:256] (C-layout, one-time) ----
    const float b1v = b1[ncol];
    f32x16 base;
    #pragma unroll
    for (int r = 0; r < 16; ++r) base[r] = b1v;
    for (int kb = 0; kb < 16; ++kb) {
        const float* src = (kb < 8) ? proj : enc;
        const int kloc = (kb & 7) * 16 + half * 8;
        const float* ap = src + (long)(b_base + l31) * 128 + kloc;
        float av[8];
        *(float4*)(av)     = *(const float4*)(ap);
        *(float4*)(av + 4) = *(const float4*)(ap + 4);
        bf16x8 ah, al, bh, bl;
        #pragma unroll
        for (int j = 0; j < 8; ++j) {
            short2 s = split1(av[j]);
            ah[j] = s.x; al[j] = s.y;
        }
        #pragma unroll
        for (int j = 0; j < 8; ++j) {
            short2 s = split1(W1[(kb * 16 + half * 8 + j) * 128 + ncol]);
            bh[j] = s.x; bl[j] = s.y;
        }
        base = MFMA(ah, bh, base);
        base = MFMA(al, bh, base);
        base = MFMA(ah, bl, base);
    }

    // ---- per-lane replicated state for row l31 (half0 lanes own state/env;
    //      half1 lanes own the mc slice k=8..15) ----
    const long sbr = b_base + l31;
    const float* idp = idm + sbr * (long)(T_STEPS * FEATC);
    const float* mcp = mc  + sbr * (long)(T_STEPS * MDC);
    float mn[8], is[8];
    #pragma unroll
    for (int k = 0; k < 8; ++k) { mn[k] = env_mean[k]; is[k] = rsqrtf(env_var[k]); }
    const float b3r = b3[0];

    float ego_v = 0.f, ego_x = 0.f, disp = 0.f;
    float nv1 = 0.f, nv2 = 0.f, nv4 = 0.f, nv5 = 0.f, nv12 = 0.f, nv13 = 0.f;
    float nm0 = 0.f, nm1 = 0.f, nm2 = 0.f;
    bf16x8 ahe, ale;   // env A-fragment for the NEXT P1 (built in tail/init)
    {
        float v8[8];
        if (half == 0) {
            ego_v = idp[0]; ego_x = idp[3]; disp = 0.f;
            const float a0 = idp[11];
            v8[0] = (ego_v - mn[0]) * is[0];
            v8[1] = (idp[1] - mn[1]) * is[1];
            v8[2] = (a0 - mn[2]) * is[2];
            v8[3] = (idp[12] - mn[3]) * is[3];
            v8[4] = (ego_v - idp[1] - mn[4]) * is[4];
            v8[5] = (idp[4] - ego_x - mn[5]) * is[5];
            v8[6] = ((ego_v - idp[2]) * idp[13] - mn[6]) * is[6];
            v8[7] = ((idp[5] - ego_x) * idp[13] + (1.f - idp[13]) * 50.f - mn[7]) * is[7];
            nv1 = idp[FEATC + 1];  nv2 = idp[FEATC + 2];
            nv4 = idp[FEATC + 4];  nv5 = idp[FEATC + 5];
            nv12 = idp[FEATC + 12]; nv13 = idp[FEATC + 13];
        } else {
            v8[0] = mcp[0]; v8[1] = mcp[1]; v8[2] = mcp[2];
            v8[3] = 0.f; v8[4] = 0.f; v8[5] = 0.f; v8[6] = 0.f; v8[7] = 0.f;
            nm0 = mcp[MDC]; nm1 = mcp[MDC + 1]; nm2 = mcp[MDC + 2];
        }
        #pragma unroll
        for (int j = 0; j < 8; ++j) {
            short2 s = split1(v8[j]);
            ahe[j] = s.x; ale[j] = s.y;
        }
        if (nq == 0 && half == 0) out[sbr * 51] = 0.f;
    }

    for (int t = 0; t < T_STEPS; ++t) {
        // ---- P1: h1 = leaky(base1 + env@W1x); split once; packed -> s_h1p ----
        {
            f32x16 acc = base;
            acc = MFMA(ahe, w1xh, acc);
            acc = MFMA(ale, w1xh, acc);
            acc = MFMA(ahe, w1xl, acc);
            #pragma unroll
            for (int r = 0; r < 16; ++r) {
                const int roff = (r & 3) + 8 * (r >> 2);
                wp[roff * PS] = packsplit(leaky(acc[r]));
            }
        }
        __syncthreads();   // barrier A: h1 write -> read (also protects s_part reuse)

        // ---- P3: layer2 TRANSPOSED (h2^T): per kb 2x b128 + 8 perm + 3 MFMA.
        //      Epilogue: in-register layer-3 partial row-sum. ----
        {
            f32x16 acc;
            #pragma unroll
            for (int r = 0; r < 16; ++r) acc[r] = 0.f;
            #pragma unroll
            for (int kb = 0; kb < 8; ++kb) {
                u32x4 q0 = *reinterpret_cast<const u32x4*>(rp + kb * 16);
                u32x4 q1 = *reinterpret_cast<const u32x4*>(rp + kb * 16 + 4);
                u32x4 hh, ll;
                hh[0] = __builtin_amdgcn_perm(q0[1], q0[0], 0x05040100u);
                hh[1] = __builtin_amdgcn_perm(q0[3], q0[2], 0x05040100u);
                hh[2] = __builtin_amdgcn_perm(q1[1], q1[0], 0x05040100u);
                hh[3] = __builtin_amdgcn_perm(q1[3], q1[2], 0x05040100u);
                ll[0] = __builtin_amdgcn_perm(q0[1], q0[0], 0x07060302u);
                ll[1] = __builtin_amdgcn_perm(q0[3], q0[2], 0x07060302u);
                ll[2] = __builtin_amdgcn_perm(q1[1], q1[0], 0x07060302u);
                ll[3] = __builtin_amdgcn_perm(q1[3], q1[2], 0x07060302u);
                bf16x8 ah2 = __builtin_bit_cast(bf16x8, hh);
                bf16x8 al2 = __builtin_bit_cast(bf16x8, ll);
                // D[m=out][n=row]: A = W2^T frags, B = h1 frags
                acc = MFMA(w2h[kb], ah2, acc);
                acc = MFMA(w2h[kb], al2, acc);
                acc = MFMA(w2l[kb], ah2, acc);
            }
            float ps = 0.f;
            #pragma unroll
            for (int g = 0; g < 4; ++g) {
                const float* bwg = bwp + 16 * g;   // outs nq*32+4*half+8*g+0..3
                float4 x0 = *(const float4*)(bwg);
                float4 x1 = *(const float4*)(bwg + 4);
                ps += leaky(acc[4 * g + 0] + x0.x) * x0.y;
                ps += leaky(acc[4 * g + 1] + x0.z) * x0.w;
                ps += leaky(acc[4 * g + 2] + x1.x) * x1.y;
                ps += leaky(acc[4 * g + 3] + x1.z) * x1.w;
            }
            ps += __shfl_xor(ps, 32);              // combine the two out-halves
            if (half == 0) s_part[l31 * 4 + nq] = ps;
        }
        __syncthreads();   // barrier B: partials ready

        // ---- tail (no barrier after): a, state, outputs, env(t+1) in-register ----
        {
            float4 pp = *(const float4*)(s_part + l31 * 4);
            const float a = pp.x + pp.y + pp.z + pp.w + b3r;
            const float move = ego_v * DT_C + 0.5f * a * DT_C * DT_C;
            disp  += move;
            ego_x += move;
            ego_v += a * DT_C;
            if (nq == 0 && half == 0) {
                out[sbr * 51 + t + 1] = disp;
                out[ACT_OFF + sbr * 50 + t] = a;
            }
            if (t < T_STEPS - 1) {
                float v8[8];
                if (half == 0) {
                    v8[0] = (ego_v - mn[0]) * is[0];
                    v8[1] = (nv1 - mn[1]) * is[1];
                    v8[2] = (a - mn[2]) * is[2];
                    v8[3] = (nv12 - mn[3]) * is[3];
                    v8[4] = (ego_v - nv1 - mn[4]) * is[4];
                    v8[5] = (nv4 - ego_x - mn[5]) * is[5];
                    v8[6] = ((ego_v - nv2) * nv13 - mn[6]) * is[6];
                    v8[7] = ((nv5 - ego_x) * nv13 + (1.f - nv13) * 50.f - mn[7]) * is[7];
                } else {
                    v8[0] = nm0; v8[1] = nm1; v8[2] = nm2;
                    v8[3] = 0.f; v8[4] = 0.f; v8[5] = 0.f; v8[6] = 0.f; v8[7] = 0.f;
                }
                #pragma unroll
                for (int j = 0; j < 8; ++j) {
                    short2 s = split1(v8[j]);
                    ahe[j] = s.x; ale[j] = s.y;
                }
                const int tn = (t + 2 < T_STEPS) ? t + 2 : T_STEPS - 1;
                if (half == 0) {
                    const float* rn = idp + tn * FEATC;
                    nv1 = rn[1]; nv2 = rn[2]; nv4 = rn[4]; nv5 = rn[5];
                    nv12 = rn[12]; nv13 = rn[13];
                } else {
                    const float* mrn = mcp + tn * MDC;
                    nm0 = mrn[0]; nm1 = mrn[1]; nm2 = mrn[2];
                }
            }
        }
    }
}

extern "C" void kernel_launch(void* const* d_in, const int* in_sizes, int n_in,
                              void* d_out, int out_size, void* d_ws, size_t ws_size,
                              hipStream_t stream) {
    const float* proj     = (const float*)d_in[0];
    const float* enc      = (const float*)d_in[1];
    const float* idm      = (const float*)d_in[2];
    const float* mcs      = (const float*)d_in[3];
    const float* env_mean = (const float*)d_in[4];
    const float* env_var  = (const float*)d_in[5];
    const float* W1       = (const float*)d_in[6];
    const float* b1       = (const float*)d_in[7];
    const float* W2       = (const float*)d_in[8];
    const float* b2       = (const float*)d_in[9];
    const float* W3       = (const float*)d_in[10];
    const float* b3       = (const float*)d_in[11];

    fwd_sim<<<B_TOT / NB, NTHR, 0, stream>>>(
        proj, enc, idm, mcs, env_mean, env_var,
        W1, b1, W2, b2, W3, b3, (float*)d_out);
}

// Round 20
// 385.003 us; speedup vs baseline: 1.0503x; 1.0503x over previous
//
#include <hip/hip_runtime.h>

// ForwardSim: B=32768, T=50 sequential steps of a 267->128->128->1 MLP.
// R1 1087 / R5 445 / R6 402 / R7 828 REGRESSION (forced VGPR64 -> spill) /
// R8 387 (4-wave blocks, 4 barrier domains; rocprof 283, VALU 52, Mfma 30) /
// R9 404 (transposed L2 + in-reg L3, 2 barriers: rocprof 300 — WORSE; barrier
//   count was not the limiter; longer serial tail chain offset the saving).
// R10: revert to R8 structure + DUAL ACCUMULATOR in P3. All 24 P3 MFMAs
//   accumulated into ONE acc -> serial 24-deep dependency chain (in-order
//   issue; MfmaUtil stuck ~27-30% across R6/R8/R9 = latency-bound pipe).
//   Split: even kb -> acc0 (seeded b2), odd kb -> acc1 (seeded 0), MFMAs
//   interleaved in program order -> two independent 12-chains, 2x MFMA ILP.
//   Epilogue merges leaky(acc0+acc1)*w3v (fp32 reorder only; R9 showed
//   reorder keeps absmax 0.125). Everything else identical to R8.
//   VGPR watch: 104 -> ~120-130; >128 would drop 4->3 blocks/CU (visible).

using bf16x8 = __attribute__((ext_vector_type(8))) short;
using f32x16 = __attribute__((ext_vector_type(16))) float;
using u32x4  = __attribute__((ext_vector_type(4))) unsigned int;

constexpr int B_TOT   = 32768;
constexpr int T_STEPS = 50;
constexpr int FEATC   = 14;
constexpr int MDC     = 3;
constexpr float ALPHA_C = 0.3f;
constexpr float DT_C    = 0.1f;

constexpr int NB   = 32;     // batch elems per block (one independent group)
constexpr int NTHR = 256;    // 4 waves; wave nq owns output cols nq*32..nq*32+31
constexpr int PS   = 132;    // dword stride: %4==0 (b128 align), 132%32=4 ->
                             // 4-way b128 read alias (LDS BW floor); writes conflict-free
constexpr int ENVS = 18;     // s_env row stride (pad, k=11..15 zero)

__device__ __forceinline__ float leaky(float x) { return fmaxf(x, ALPHA_C * x); }

// split fp32 into bf16 hi (truncate) + bf16 lo (truncated exact residual); by value
__device__ __forceinline__ short2 split1(float x) {
    unsigned u = __float_as_uint(x);
    short h = (short)(u >> 16);
    float r = x - __uint_as_float(u & 0xFFFF0000u);   // exact in fp32
    short l = (short)(__float_as_uint(r) >> 16);
    return make_short2(h, l);
}

// same split, packed into one dword: low16 = hi bf16, high16 = lo bf16
__device__ __forceinline__ unsigned packsplit(float x) {
    unsigned u = __float_as_uint(x);
    float r = x - __uint_as_float(u & 0xFFFF0000u);   // exact in fp32
    return (u >> 16) | (__float_as_uint(r) & 0xFFFF0000u);
}

#define MFMA(A, B, C) __builtin_amdgcn_mfma_f32_32x32x16_bf16(A, B, C, 0, 0, 0)

__launch_bounds__(NTHR, 2)
__global__ void fwd_sim(const float* __restrict__ proj,
                        const float* __restrict__ enc,
                        const float* __restrict__ idm,
                        const float* __restrict__ mc,
                        const float* __restrict__ env_mean,
                        const float* __restrict__ env_var,
                        const float* __restrict__ W1,
                        const float* __restrict__ b1,
                        const float* __restrict__ W2,
                        const float* __restrict__ b2,
                        const float* __restrict__ W3,
                        const float* __restrict__ b3,
                        float* __restrict__ out)
{
    __shared__ unsigned s_h1p[NB * PS];  // h1 packed (bf16 hi | lo<<16), P1 -> P3
    __shared__ float    s_p  [NB * PS];  // p = leaky(h2)*W3col, P3 -> P4
    __shared__ float    s_env[NB * ENVS];// [env(8) | mc(3) | zeros(pad to 16) | pad]

    const int tid  = threadIdx.x;
    const int lane = tid & 63;
    const int nq   = (tid >> 6) & 3;  // wave 0..3 = n-quarter
    const int l31  = lane & 31;
    const int half = lane >> 5;       // k-half within fragment
    const int ncol = nq * 32 + l31;   // output column 0..127 (C/D: col = lane&31)
    const int am   = l31;             // A-row (local batch) for A-fragments
    const int b_base = blockIdx.x * NB;
    const long ACT_OFF = (long)B_TOT * 51;

    // zero s_env (pad cols must stay 0 forever)
    for (int i = tid; i < NB * ENVS; i += NTHR) s_env[i] = 0.f;
    __syncthreads();

    const float b1v = b1[ncol];
    const float b2v = b2[ncol];
    const float w3v = W3[ncol];

    // phase base pointers (all immediate-offset addressable in the t-loop)
    unsigned*       wp = s_h1p + (4 * half) * PS + ncol;  // P1 packed write
    const unsigned* rp = s_h1p + am * PS + half * 8;      // P3 fragment read
    float*          pw = s_p   + (4 * half) * PS + ncol;  // P3 p write

    // ---- W2 -> pre-split B-fragments in registers (one-time) ----
    // B frag (32x32x16): lane holds B[k = half*8 + j][n = lane&31]
    bf16x8 w2h[8], w2l[8];
    for (int kb = 0; kb < 8; ++kb) {
        #pragma unroll
        for (int j = 0; j < 8; ++j) {
            short2 s = split1(W2[(kb * 16 + half * 8 + j) * 128 + ncol]);
            w2h[kb][j] = s.x; w2l[kb][j] = s.y;
        }
    }
    // ---- W1 rows 256..266 (env+mc), K padded to 16 ----
    bf16x8 w1xh, w1xl;
    #pragma unroll
    for (int j = 0; j < 8; ++j) {
        int k = half * 8 + j;
        short2 s = split1(k < 11 ? W1[(256 + k) * 128 + ncol] : 0.f);
        w1xh[j] = s.x; w1xl[j] = s.y;
    }

    // ---- base1 = b1 + [proj|enc] @ W1[0:256]  (C-layout registers, one-time) ----
    f32x16 base;
    #pragma unroll
    for (int r = 0; r < 16; ++r) base[r] = b1v;
    for (int kb = 0; kb < 16; ++kb) {
        const float* src = (kb < 8) ? proj : enc;
        const int kloc = (kb & 7) * 16 + half * 8;
        const float* ap = src + (long)(b_base + am) * 128 + kloc;
        float av[8];
        *(float4*)(av)     = *(const float4*)(ap);
        *(float4*)(av + 4) = *(const float4*)(ap + 4);
        bf16x8 ah, al, bh, bl;
        #pragma unroll
        for (int j = 0; j < 8; ++j) {
            short2 s = split1(av[j]);
            ah[j] = s.x; al[j] = s.y;
        }
        #pragma unroll
        for (int j = 0; j < 8; ++j) {
            short2 s = split1(W1[(kb * 16 + half * 8 + j) * 128 + ncol]);
            bh[j] = s.x; bl[j] = s.y;
        }
        base = MFMA(ah, bh, base);
        base = MFMA(al, bh, base);
        base = MFMA(ah, bl, base);
    }

    // ---- distributed per-batch state: lane (tid&7)==0 owns batch row tid>>3 ----
    const bool act = (tid & 7) == 0;
    const int  sm  = tid >> 3;          // state row 0..31 when act
    const long sb  = b_base + sm;
    float ego_v = 0.f, ego_a = 0.f, ego_x = 0.f, disp = 0.f, b3r = 0.f;
    float mn[8], is[8];
    float nv1 = 0.f, nv2 = 0.f, nv4 = 0.f, nv5 = 0.f, nv12 = 0.f, nv13 = 0.f;
    float nm0 = 0.f, nm1 = 0.f, nm2 = 0.f;
    if (act) {
        #pragma unroll
        for (int k = 0; k < 8; ++k) { mn[k] = env_mean[k]; is[k] = rsqrtf(env_var[k]); }
        b3r = b3[0];
        const float* r0 = idm + sb * (T_STEPS * FEATC);
        const float* m0 = mc  + sb * (T_STEPS * MDC);
        ego_v = r0[0]; ego_a = r0[11]; ego_x = r0[3]; disp = 0.f;
        out[sb * 51] = 0.f;
        float e[8];
        e[0] = ego_v; e[1] = r0[1]; e[2] = ego_a; e[3] = r0[12];
        e[4] = ego_v - r0[1];
        e[5] = r0[4] - ego_x;
        e[6] = (ego_v - r0[2]) * r0[13];
        e[7] = (r0[5] - ego_x) * r0[13] + (1.f - r0[13]) * 50.f;
        #pragma unroll
        for (int k = 0; k < 8; ++k) s_env[sm * ENVS + k] = (e[k] - mn[k]) * is[k];
        s_env[sm * ENVS + 8]  = m0[0];
        s_env[sm * ENVS + 9]  = m0[1];
        s_env[sm * ENVS + 10] = m0[2];
        // prefetch idm/mc row 1
        nv1 = r0[FEATC + 1]; nv2 = r0[FEATC + 2]; nv4 = r0[FEATC + 4];
        nv5 = r0[FEATC + 5]; nv12 = r0[FEATC + 12]; nv13 = r0[FEATC + 13];
        nm0 = m0[MDC]; nm1 = m0[MDC + 1]; nm2 = m0[MDC + 2];
    }
    __syncthreads();

    for (int t = 0; t < T_STEPS; ++t) {
        // ---- P1: h1 = leaky(base1 + [env,mc]@W1x), split ONCE, packed -> s_h1p ----
        {
            const float* ep = s_env + am * ENVS + half * 8;
            float av[8];
            *(float2*)(av)     = *(const float2*)(ep);
            *(float2*)(av + 2) = *(const float2*)(ep + 2);
            *(float2*)(av + 4) = *(const float2*)(ep + 4);
            *(float2*)(av + 6) = *(const float2*)(ep + 6);
            bf16x8 ah, al;
            #pragma unroll
            for (int j = 0; j < 8; ++j) {
                short2 s = split1(av[j]);
                ah[j] = s.x; al[j] = s.y;
            }
            f32x16 acc = base;
            acc = MFMA(ah, w1xh, acc);
            acc = MFMA(al, w1xh, acc);
            acc = MFMA(ah, w1xl, acc);
            #pragma unroll
            for (int r = 0; r < 16; ++r) {
                const int roff = (r & 3) + 8 * (r >> 2);   // C/D row map (lane part in wp)
                wp[roff * PS] = packsplit(leaky(acc[r]));
            }
        }
        __syncthreads();

        // ---- P3: layer2 — DUAL accumulator chains. Even kb -> acc0 (+b2),
        //      odd kb -> acc1 (0-seeded); MFMAs interleaved in program order
        //      => two independent 12-deep chains instead of one 24-deep. ----
        {
            f32x16 acc0, acc1;
            #pragma unroll
            for (int r = 0; r < 16; ++r) { acc0[r] = b2v; acc1[r] = 0.f; }
            #pragma unroll
            for (int kp = 0; kp < 4; ++kp) {
                const int ka = 2 * kp, kb2 = 2 * kp + 1;
                u32x4 qa0 = *reinterpret_cast<const u32x4*>(rp + ka * 16);
                u32x4 qa1 = *reinterpret_cast<const u32x4*>(rp + ka * 16 + 4);
                u32x4 qb0 = *reinterpret_cast<const u32x4*>(rp + kb2 * 16);
                u32x4 qb1 = *reinterpret_cast<const u32x4*>(rp + kb2 * 16 + 4);
                u32x4 ha, la, hb, lb;
                ha[0] = __builtin_amdgcn_perm(qa0[1], qa0[0], 0x05040100u);
                ha[1] = __builtin_amdgcn_perm(qa0[3], qa0[2], 0x05040100u);
                ha[2] = __builtin_amdgcn_perm(qa1[1], qa1[0], 0x05040100u);
                ha[3] = __builtin_amdgcn_perm(qa1[3], qa1[2], 0x05040100u);
                la[0] = __builtin_amdgcn_perm(qa0[1], qa0[0], 0x07060302u);
                la[1] = __builtin_amdgcn_perm(qa0[3], qa0[2], 0x07060302u);
                la[2] = __builtin_amdgcn_perm(qa1[1], qa1[0], 0x07060302u);
                la[3] = __builtin_amdgcn_perm(qa1[3], qa1[2], 0x07060302u);
                hb[0] = __builtin_amdgcn_perm(qb0[1], qb0[0], 0x05040100u);
                hb[1] = __builtin_amdgcn_perm(qb0[3], qb0[2], 0x05040100u);
                hb[2] = __builtin_amdgcn_perm(qb1[1], qb1[0], 0x05040100u);
                hb[3] = __builtin_amdgcn_perm(qb1[3], qb1[2], 0x05040100u);
                lb[0] = __builtin_amdgcn_perm(qb0[1], qb0[0], 0x07060302u);
                lb[1] = __builtin_amdgcn_perm(qb0[3], qb0[2], 0x07060302u);
                lb[2] = __builtin_amdgcn_perm(qb1[1], qb1[0], 0x07060302u);
                lb[3] = __builtin_amdgcn_perm(qb1[3], qb1[2], 0x07060302u);
                bf16x8 aha = __builtin_bit_cast(bf16x8, ha);
                bf16x8 ala = __builtin_bit_cast(bf16x8, la);
                bf16x8 ahb = __builtin_bit_cast(bf16x8, hb);
                bf16x8 alb = __builtin_bit_cast(bf16x8, lb);
                acc0 = MFMA(aha, w2h[ka],  acc0);
                acc1 = MFMA(ahb, w2h[kb2], acc1);
                acc0 = MFMA(ala, w2h[ka],  acc0);
                acc1 = MFMA(alb, w2h[kb2], acc1);
                acc0 = MFMA(aha, w2l[ka],  acc0);
                acc1 = MFMA(ahb, w2l[kb2], acc1);
            }
            #pragma unroll
            for (int r = 0; r < 16; ++r) {
                const int roff = (r & 3) + 8 * (r >> 2);
                pw[roff * PS] = leaky(acc0[r] + acc1[r]) * w3v;
            }
        }
        __syncthreads();

        // ---- P4: row-sum (layer3), state update, env(t+1), outputs ----
        {
            const int row = tid >> 3, seg = tid & 7;
            const float* pp = s_p + row * PS + seg * 16;
            float s = 0.f;
            #pragma unroll
            for (int i = 0; i < 8; ++i) {
                float2 v = *(const float2*)(pp + i * 2);
                s += v.x + v.y;
            }
            s += __shfl_xor(s, 1);
            s += __shfl_xor(s, 2);
            s += __shfl_xor(s, 4);
            if (act) {
                const float a = s + b3r;
                const float move = ego_v * DT_C + 0.5f * a * DT_C * DT_C;
                disp  += move;
                ego_x += move;
                ego_v += a * DT_C;
                ego_a  = a;
                out[sb * 51 + t + 1] = disp;
                out[ACT_OFF + sb * 50 + t] = a;
                if (t < T_STEPS - 1) {
                    float e[8];
                    e[0] = ego_v; e[1] = nv1; e[2] = ego_a; e[3] = nv12;
                    e[4] = ego_v - nv1;
                    e[5] = nv4 - ego_x;
                    e[6] = (ego_v - nv2) * nv13;
                    e[7] = (nv5 - ego_x) * nv13 + (1.f - nv13) * 50.f;
                    #pragma unroll
                    for (int k = 0; k < 8; ++k) s_env[sm * ENVS + k] = (e[k] - mn[k]) * is[k];
                    s_env[sm * ENVS + 8]  = nm0;
                    s_env[sm * ENVS + 9]  = nm1;
                    s_env[sm * ENVS + 10] = nm2;
                    const int tn = (t + 2 < T_STEPS) ? t + 2 : T_STEPS - 1;
                    const float* rn = idm + sb * (T_STEPS * FEATC) + tn * FEATC;
                    const float* mrn = mc + sb * (T_STEPS * MDC) + tn * MDC;
                    nv1 = rn[1]; nv2 = rn[2]; nv4 = rn[4]; nv5 = rn[5];
                    nv12 = rn[12]; nv13 = rn[13];
                    nm0 = mrn[0]; nm1 = mrn[1]; nm2 = mrn[2];
                }
            }
        }
        __syncthreads();
    }
}

extern "C" void kernel_launch(void* const* d_in, const int* in_sizes, int n_in,
                              void* d_out, int out_size, void* d_ws, size_t ws_size,
                              hipStream_t stream) {
    const float* proj     = (const float*)d_in[0];
    const float* enc      = (const float*)d_in[1];
    const float* idm      = (const float*)d_in[2];
    const float* mcs      = (const float*)d_in[3];
    const float* env_mean = (const float*)d_in[4];
    const float* env_var  = (const float*)d_in[5];
    const float* W1       = (const float*)d_in[6];
    const float* b1       = (const float*)d_in[7];
    const float* W2       = (const float*)d_in[8];
    const float* b2       = (const float*)d_in[9];
    const float* W3       = (const float*)d_in[10];
    const float* b3       = (const float*)d_in[11];

    fwd_sim<<<B_TOT / NB, NTHR, 0, stream>>>(
        proj, enc, idm, mcs, env_mean, env_var,
        W1, b1, W2, b2, W3, b3, (float*)d_out);
}